// Round 8
// baseline (93.945 us; speedup 1.0000x reference)
//
#include <hip/hip_runtime.h>

typedef _Float16 f16x8 __attribute__((ext_vector_type(8)));
typedef float f32x4 __attribute__((ext_vector_type(4)));

#define MDIM 64000
#define KDIM 512
#define NCOLS 514
#define NPAD 512
#define BM 128
#define BN 128
#define BK 32
#define KT (KDIM / BK)  // 16
#define NT 4            // N tiles (cols 0..511); Nyquist cols 512/513 analytic
#define NWG 2000        // 500 M-tiles x 4 N-tiles, divisible by 8

// global -> LDS direct DMA, 16B per lane, LDS dest = wave-uniform base + lane*16
#define GLOAD_LDS16(g, l)                                        \
  __builtin_amdgcn_global_load_lds(                              \
      (const __attribute__((address_space(1))) void*)(g),        \
      (__attribute__((address_space(3))) void*)(l), 16, 0, 0)

// Build interleaved f16 weight matrix Wb[n][k], n in [0,512):
//   n even -> real_kernel[n/2], n odd -> imag_kernel[n/2]
__global__ void prep_w(const float* __restrict__ rk, const float* __restrict__ ik,
                       _Float16* __restrict__ wb) {
  int n = blockIdx.x;
  int k = threadIdx.x;
  int bin = n >> 1;
  const float* src = (n & 1) ? ik : rk;
  wb[(size_t)n * KDIM + k] = (_Float16)src[bin * KDIM + k];
}

__global__ __launch_bounds__(256, 2)
void dft_gemm(const float* __restrict__ x, const _Float16* __restrict__ wb,
              float* __restrict__ out) {
  // A: f32, TRIPLE-buffered (distance-2 DMA prefetch, counted vmcnt keeps the
  // newest A batch in flight across barriers). B: f16, double-buffered
  // (distance-1; wb is 512 KB L2-resident, one compute phase covers it).
  // Swizzles identical to round 6 (verified):
  //   A: logical 16B chunk c of row r at phys c^(r&7)        (8 chunks/row)
  //   B: logical 16B chunk c of row r at phys c^((r>>1)&3)   (4 chunks/row)
  __shared__ float As[3][BM * BK];     // 3 x 16 KB
  __shared__ _Float16 Bs[2][BN * BK];  // 2 x  8 KB -> 64 KB total, 2 blocks/CU

  const int tid = threadIdx.x;
  const int l   = tid & 63;
  const int w   = tid >> 6;
  const int lr  = l & 15, lg = l >> 4;
  const int wm  = (w >> 1) * 64;
  const int wn  = (w & 1) * 64;

  // T1: XCD swizzle (NWG%8==0 -> chunked bijection). Consecutive wgid -> same
  // XCD, so the 4 N-tile blocks of one M-tile share the x slab in one L2.
  const int wgid = (blockIdx.x & 7) * (NWG / 8) + (blockIdx.x >> 3);
  const int mt = wgid >> 2, nt = wgid & 3;
  const int m0 = mt * BM, n0 = nt * BN;

  f32x4 acc[4][4] = {};
  float nyq = 0.0f;

  // A staging (4 issues/thread): issue s covers rows w*32+s*8..+7.
  // lane row-in-issue = l>>3, phys chunk = l&7, logical = (l&7)^(l>>3).
  const int arow0 = w * 32 + (l >> 3);
  const float* asrc = x + (size_t)(m0 + arow0) * KDIM + (((l & 7) ^ (l >> 3)) << 2);

  // B staging (2 issues/thread): issue s covers rows w*32+s*16..+15.
  // lane row-in-issue = l>>2, phys chunk = l&3, logical = (l&3)^((l>>3)&3).
  const int brow0 = w * 32 + (l >> 2);
  const _Float16* bsrc =
      wb + (size_t)(n0 + brow0) * KDIM + (((l & 3) ^ ((l >> 3) & 3)) << 3);

#define STAGE_A(t, b)                                                   \
  {                                                                     \
    _Pragma("unroll")                                                   \
    for (int s = 0; s < 4; ++s)                                         \
      GLOAD_LDS16(asrc + (size_t)s * 8 * KDIM + (t) * BK,              \
                  &As[b][(w * 32 + s * 8) * BK]);                       \
  }

#define STAGE_B(t, b)                                                   \
  {                                                                     \
    _Pragma("unroll")                                                   \
    for (int s = 0; s < 2; ++s)                                         \
      GLOAD_LDS16(bsrc + (size_t)s * 16 * KDIM + (t) * BK,             \
                  &Bs[b][(w * 32 + s * 16) * BK]);                      \
  }

#define COMPUTE(ba, bbuf)                                              \
  {                                                                    \
    f16x8 av[4], bv[4];                                                \
    _Pragma("unroll")                                                  \
    for (int fm = 0; fm < 4; ++fm) {                                   \
      int row = wm + fm * 16 + lr;                                     \
      int sw  = lr & 7; /* row&7 */                                    \
      int c0  = lg * 2;                                                \
      f32x4 lo = *reinterpret_cast<const f32x4*>(                      \
          &As[ba][row * BK + ((c0 ^ sw) << 2)]);                       \
      f32x4 hi = *reinterpret_cast<const f32x4*>(                      \
          &As[ba][row * BK + (((c0 + 1) ^ sw) << 2)]);                 \
      f16x8 h;                                                         \
      h[0] = (_Float16)lo[0]; h[1] = (_Float16)lo[1];                  \
      h[2] = (_Float16)lo[2]; h[3] = (_Float16)lo[3];                  \
      h[4] = (_Float16)hi[0]; h[5] = (_Float16)hi[1];                  \
      h[6] = (_Float16)hi[2]; h[7] = (_Float16)hi[3];                  \
      av[fm] = h;                                                      \
    }                                                                  \
    _Pragma("unroll")                                                  \
    for (int fn = 0; fn < 4; ++fn) {                                   \
      int row = wn + fn * 16 + lr;                                     \
      int c   = lg ^ ((lr >> 1) & 3); /* (row>>1)&3 */                 \
      bv[fn] = *reinterpret_cast<const f16x8*>(&Bs[bbuf][row * BK + (c << 3)]); \
    }                                                                  \
    _Pragma("unroll")                                                  \
    for (int fm = 0; fm < 4; ++fm)                                     \
      _Pragma("unroll")                                                \
      for (int fn = 0; fn < 4; ++fn)                                   \
        acc[fm][fn] = __builtin_amdgcn_mfma_f32_16x16x32_f16(          \
            av[fm], bv[fn], acc[fm][fn], 0, 0, 0);                     \
  }

  // Nyquist alternating sum from the landed A tile (nt==0 blocks only).
  const int nrow = tid >> 1;
#define NYQ(ba)                                                        \
  {                                                                    \
    _Pragma("unroll")                                                  \
    for (int j = 0; j < 4; ++j) {                                      \
      int c = ((tid & 1) * 4 + j) ^ (nrow & 7);                        \
      f32x4 v = *reinterpret_cast<const f32x4*>(&As[ba][nrow * BK + (c << 2)]); \
      nyq += (v[0] - v[1]) + (v[2] - v[3]);                            \
    }                                                                  \
  }

  // ---- prologue: B(0), A(0), A(1); wait all but A(1)'s 4 loads ----
  STAGE_B(0, 0);
  __builtin_amdgcn_sched_barrier(0);
  STAGE_A(0, 0);
  __builtin_amdgcn_sched_barrier(0);
  STAGE_A(1, 1);
  __builtin_amdgcn_sched_barrier(0);
  asm volatile("s_waitcnt vmcnt(4)");
  __builtin_amdgcn_s_barrier();
  __builtin_amdgcn_sched_barrier(0);

  // ---- K loop: distance-2 A prefetch, counted vmcnt(4) at the barrier ----
  for (int t = 0; t < KT; ++t) {
    const int ba = t % 3, bbuf = t & 1;
    if (t + 1 < KT) {  // B first: FIFO-oldest among this iter's issues
      STAGE_B(t + 1, (t + 1) & 1);
      __builtin_amdgcn_sched_barrier(0);
    }
    if (t + 2 < KT) {
      STAGE_A(t + 2, (t + 2) % 3);
      __builtin_amdgcn_sched_barrier(0);
    }
    COMPUTE(ba, bbuf);
    if (nt == 0) NYQ(ba);
    if (t + 1 < KT) {
      __builtin_amdgcn_sched_barrier(0);
      // lgkmcnt(0): my LDS reads retired before signaling (write-after-read
      // guard). vmcnt(4): A(t+1)+B(t+1) landed, A(t+2) stays in flight.
      if (t < KT - 2) asm volatile("s_waitcnt vmcnt(4) lgkmcnt(0)");
      else            asm volatile("s_waitcnt vmcnt(0) lgkmcnt(0)");
      __builtin_amdgcn_s_barrier();
      __builtin_amdgcn_sched_barrier(0);
    }
  }

  // ---- epilogue: C/D layout col=lane&15, row=(lane>>4)*4+reg ----
#pragma unroll
  for (int fm = 0; fm < 4; ++fm) {
#pragma unroll
    for (int rr = 0; rr < 4; ++rr) {
      int row = m0 + wm + fm * 16 + lg * 4 + rr;
      size_t base = (size_t)row * NCOLS;
#pragma unroll
      for (int fn = 0; fn < 4; ++fn)
        out[base + n0 + wn + fn * 16 + lr] = acc[fm][fn][rr];
    }
  }

  // ---- Nyquist bin: col 512 = alternating sum, col 513 = 0 ----
  if (nt == 0) {
    float tot = nyq + __shfl_xor(nyq, 1);
    if ((tid & 1) == 0) {
      size_t base = (size_t)(m0 + nrow) * NCOLS;
      out[base + 512] = tot;
      out[base + 513] = 0.0f;
    }
  }
#undef STAGE_A
#undef STAGE_B
#undef COMPUTE
#undef NYQ
}

extern "C" void kernel_launch(void* const* d_in, const int* in_sizes, int n_in,
                              void* d_out, int out_size, void* d_ws, size_t ws_size,
                              hipStream_t stream) {
  const float* x  = (const float*)d_in[0];
  const float* rk = (const float*)d_in[1];
  const float* ik = (const float*)d_in[2];
  float* out = (float*)d_out;
  _Float16* wb = (_Float16*)d_ws;  // 512*512*2 B = 512 KB scratch

  prep_w<<<dim3(NPAD), dim3(KDIM), 0, stream>>>(rk, ik, wb);

  dim3 grid(NWG);
  dft_gemm<<<grid, dim3(256), 0, stream>>>(x, wb, out);
}

// Round 9
// 78.244 us; speedup vs baseline: 1.2007x; 1.2007x over previous
//
#include <hip/hip_runtime.h>

typedef _Float16 f16x8 __attribute__((ext_vector_type(8)));
typedef float f32x4 __attribute__((ext_vector_type(4)));

#define MDIM 64000
#define KDIM 512
#define NCOLS 514
#define NPAD 512
#define BM 128
#define BN 128
#define BK 64
#define KT (KDIM / BK)  // 8
#define NT 4            // N tiles (cols 0..511); Nyquist cols 512/513 analytic
#define NWG 2000        // 500 M-tiles x 4 N-tiles, divisible by 8

// global -> LDS direct DMA, 16B per lane, LDS dest = wave-uniform base + lane*16
#define GLOAD_LDS16(g, l)                                        \
  __builtin_amdgcn_global_load_lds(                              \
      (const __attribute__((address_space(1))) void*)(g),        \
      (__attribute__((address_space(3))) void*)(l), 16, 0, 0)

// Build interleaved f16 weight matrix Wb[n][k], n in [0,512):
//   n even -> real_kernel[n/2], n odd -> imag_kernel[n/2]
__global__ void prep_w(const float* __restrict__ rk, const float* __restrict__ ik,
                       _Float16* __restrict__ wb) {
  int n = blockIdx.x;
  int k = threadIdx.x;
  int bin = n >> 1;
  const float* src = (n & 1) ? ik : rk;
  wb[(size_t)n * KDIM + k] = (_Float16)src[bin * KDIM + k];
}

__global__ __launch_bounds__(256, 3)
void dft_gemm(const float* __restrict__ x, const _Float16* __restrict__ wb,
              float* __restrict__ out) {
  // P2 structure (best measured): single-buffered, all-global_load_lds,
  // A kept f32 in LDS (cvt on fragment read), two full barriers per K-step.
  // Chunk-swizzle: logical 16B-chunk c of row r lives at physical c^(r&7),
  // achieved by inverse-swizzling the GLOBAL source address (LDS dest linear).
  __shared__ float As[BM * BK];      // 32 KB
  __shared__ _Float16 Bs[BN * BK];   // 16 KB -> 48 KB total, 3 blocks/CU

  const int tid = threadIdx.x;
  const int l   = tid & 63;
  const int w   = tid >> 6;
  const int lr  = l & 15;   // fragment row/col lane index
  const int lg  = l >> 4;   // lane k-group 0..3
  const int wm  = (w >> 1) * 64;
  const int wn  = (w & 1) * 64;

  // T1: XCD swizzle (NWG%8==0 -> chunked bijection). Consecutive wgid -> same
  // XCD, so the 4 N-tile blocks of one M-tile share the x slab in one L2.
  const int wgid = (blockIdx.x & 7) * (NWG / 8) + (blockIdx.x >> 3);
  const int mt = wgid >> 2;
  const int nt = wgid & 3;
  const int m0 = mt * BM;
  const int n0 = nt * BN;

  f32x4 acc[4][4] = {};
  float nyq = 0.0f;

  // staging lane decomposition (identical to P2)
  const int arl = l >> 4;  // A: row-within-issue 0..3
  const int acp = l & 15;  // A: phys 16B chunk 0..15 (4 floats)
  const int brl = l >> 3;  // B: row-within-issue 0..7
  const int bcp = l & 7;   // B: phys 16B chunk 0..7 (8 f16)

  for (int kt = 0; kt < KT; ++kt) {
    if (kt) __syncthreads();  // WAR: prior tile's LDS reads retired

    // ---- stage A: x f32 -> LDS via global_load_lds, source pre-swizzled ----
#pragma unroll
    for (int s = 0; s < 8; ++s) {
      int r0  = w * 32 + s * 4;            // wave-uniform
      int row = r0 + arl;
      int cl  = acp ^ (row & 7);           // logical chunk to fetch
      const float* g = x + (size_t)(m0 + row) * KDIM + kt * BK + cl * 4;
      GLOAD_LDS16(g, &As[r0 * BK]);
    }
    // ---- stage B: wb f16 -> LDS via global_load_lds, source pre-swizzled ----
#pragma unroll
    for (int s = 0; s < 4; ++s) {
      int r0  = w * 32 + s * 8;            // wave-uniform
      int row = r0 + brl;
      int cl  = bcp ^ (row & 7);
      const _Float16* g = wb + (size_t)(n0 + row) * KDIM + kt * BK + cl * 8;
      GLOAD_LDS16(g, &Bs[r0 * BK]);
    }
    __syncthreads();  // drains vmcnt(0): tile landed

    // ---- MFMA: 2 k-subtiles of 32, 4x4 fragments of 16x16 per wave ----
#pragma unroll
    for (int ks = 0; ks < 2; ++ks) {
      f16x8 av[4], bv[4];
#pragma unroll
      for (int fm = 0; fm < 4; ++fm) {
        int row = wm + fm * 16 + lr;
        int c0  = ks * 8 + lg * 2;         // logical 16B chunk (4 f32)
        int sw  = row & 7;
        f32x4 lo = *reinterpret_cast<const f32x4*>(&As[row * BK + ((c0 ^ sw) << 2)]);
        f32x4 hi = *reinterpret_cast<const f32x4*>(&As[row * BK + (((c0 + 1) ^ sw) << 2)]);
        f16x8 h;
        h[0] = (_Float16)lo[0]; h[1] = (_Float16)lo[1];
        h[2] = (_Float16)lo[2]; h[3] = (_Float16)lo[3];
        h[4] = (_Float16)hi[0]; h[5] = (_Float16)hi[1];
        h[6] = (_Float16)hi[2]; h[7] = (_Float16)hi[3];
        av[fm] = h;
      }
#pragma unroll
      for (int fn = 0; fn < 4; ++fn) {
        int row = wn + fn * 16 + lr;
        int c   = (ks * 4 + lg) ^ (row & 7);  // 16B chunk (8 f16)
        bv[fn] = *reinterpret_cast<const f16x8*>(&Bs[row * BK + (c << 3)]);
      }
#pragma unroll
      for (int fm = 0; fm < 4; ++fm)
#pragma unroll
        for (int fn = 0; fn < 4; ++fn)
          acc[fm][fn] = __builtin_amdgcn_mfma_f32_16x16x32_f16(
              av[fm], bv[fn], acc[fm][fn], 0, 0, 0);
    }

    // ---- Nyquist alternating sum from the landed f32 A tile (nt==0) ----
    // phys chunk c holds logical c^(row&7); logical chunk L starts at col
    // kt*64 + L*4 (even) -> signs +,-,+,- within each f32x4.
    if (nt == 0) {
      const int nrow = tid >> 1;
      const int half = tid & 1;
#pragma unroll
      for (int j = 0; j < 8; ++j) {
        int c = (half * 8 + j) ^ (nrow & 7);
        f32x4 v = *reinterpret_cast<const f32x4*>(&As[nrow * BK + (c << 2)]);
        nyq += (v[0] - v[1]) + (v[2] - v[3]);
      }
    }
  }

  // ---- epilogue: C/D layout col=lane&15, row=(lane>>4)*4+reg ----
#pragma unroll
  for (int fm = 0; fm < 4; ++fm) {
#pragma unroll
    for (int rr = 0; rr < 4; ++rr) {
      int row = m0 + wm + fm * 16 + lg * 4 + rr;
      size_t base = (size_t)row * NCOLS;
#pragma unroll
      for (int fn = 0; fn < 4; ++fn)
        out[base + n0 + wn + fn * 16 + lr] = acc[fm][fn][rr];
    }
  }

  // ---- Nyquist bin: col 512 = sum_n (-1)^n x[n], col 513 = 0 ----
  if (nt == 0) {
    float tot = nyq + __shfl_xor(nyq, 1);
    if ((tid & 1) == 0) {
      size_t base = (size_t)(m0 + (tid >> 1)) * NCOLS;
      out[base + 512] = tot;
      out[base + 513] = 0.0f;
    }
  }
}

extern "C" void kernel_launch(void* const* d_in, const int* in_sizes, int n_in,
                              void* d_out, int out_size, void* d_ws, size_t ws_size,
                              hipStream_t stream) {
  const float* x  = (const float*)d_in[0];
  const float* rk = (const float*)d_in[1];
  const float* ik = (const float*)d_in[2];
  float* out = (float*)d_out;
  _Float16* wb = (_Float16*)d_ws;  // 512*512*2 B = 512 KB scratch

  prep_w<<<dim3(NPAD), dim3(KDIM), 0, stream>>>(rk, ik, wb);

  dim3 grid(NWG);
  dft_gemm<<<grid, dim3(256), 0, stream>>>(x, wb, out);
}